// Round 5
// baseline (781.746 us; speedup 1.0000x reference)
//
#include <hip/hip_runtime.h>
#include <hip/hip_bf16.h>
#include <cstdint>

// ---------------------------------------------------------------------------
// ThreeLayerCNN (BranchyNet early-exit), B=4096.
// Precision: conv1/conv2/exit1/exit2 fp32 (argmax parity with numpy ref);
// big FC GEMMs (l1c1, l1c2) bf16 MFMA w/ fp32 accum (output tol 0.146).
// Round 16 (r15 post-mortem: gemm shadowed, conv2 is LDS-issue-bound --
// 15 ds_read_b128 weight reads per 180 FMA = ~78% of stage1 LDS cycles):
//  - conv2: 2 images/block, SAME (ocg,pos) mapping, accA/accB[5][4].
//    Each 3xb128 weight read now feeds 72 FMAs (2 img) -> weight LDS
//    traffic and weight L2 re-fetch both halve. No launch bounds (r12
//    lesson), oc stays 5 (acc 40 regs), weights stay in LDS.
//    h2 BIT-IDENTICAL: per-output ic order 0..49 + verbatim tap tree.
//  - everything else byte-identical to r15 (best: 712 us): bf16 mirrors
//    h1b/h2b feeding bare-copy GEMM A-staging, wb16v8, conv3x+exit2 fold.
// ---------------------------------------------------------------------------

typedef __bf16 bf16_t;
typedef __bf16 bf16x8 __attribute__((ext_vector_type(8)));
typedef float  f32x4  __attribute__((ext_vector_type(4)));

#define B_IMG 4096

// ======================= role bodies (device functions) =====================

__device__ void role_conv1(char* smem, int blk,
    const float* __restrict__ x, const float* __restrict__ w1,
    const float* __restrict__ b1, float* __restrict__ h1,
    bf16_t* __restrict__ h1b)
{
    float* ws = (float*)smem;        // 450
    float* bs = ws + 456;            // 50
    const int t = threadIdx.x;
    for (int i = t; i < 450; i += 256) ws[i] = w1[i];
    if (t < 50) bs[t] = b1[t];
    __syncthreads();

    const int idx = blk * 256 + t;
    if (idx >= B_IMG * 169) return;
    const int b   = idx / 169;
    const int pos = idx % 169;
    const int py = pos / 13, px = pos % 13;

    const float* xp = x + (size_t)b * 784 + (2 * py) * 28 + 2 * px;
    float p[4][4];
#pragma unroll
    for (int r = 0; r < 4; ++r)
#pragma unroll
        for (int c = 0; c < 4; ++c) p[r][c] = xp[r * 28 + c];

    float*  hb  = h1  + (size_t)b * 8480 + pos;
    bf16_t* hbb = h1b + (size_t)b * 8480 + pos;
    if (pos < 30) {
        h1 [(size_t)b * 8480 + 8450 + pos] = 0.f;            // zero pad cols
        h1b[(size_t)b * 8480 + 8450 + pos] = (bf16_t)0.f;
    }

    for (int oc = 0; oc < 50; ++oc) {
        const float* wp = &ws[oc * 9];
        const float w00 = wp[0], w01 = wp[1], w02 = wp[2];
        const float w10 = wp[3], w11 = wp[4], w12 = wp[5];
        const float w20 = wp[6], w21 = wp[7], w22 = wp[8];
        float a[2][2];
#pragma unroll
        for (int dy = 0; dy < 2; ++dy)
#pragma unroll
            for (int dx = 0; dx < 2; ++dx) {
                a[dy][dx] = p[dy + 0][dx + 0] * w00 + p[dy + 0][dx + 1] * w01 + p[dy + 0][dx + 2] * w02
                          + p[dy + 1][dx + 0] * w10 + p[dy + 1][dx + 1] * w11 + p[dy + 1][dx + 2] * w12
                          + p[dy + 2][dx + 0] * w20 + p[dy + 2][dx + 1] * w21 + p[dy + 2][dx + 2] * w22;
            }
        float v = fmaxf(fmaxf(a[0][0], a[0][1]), fmaxf(a[1][0], a[1][1])) + bs[oc];
        const float r = fmaxf(v, 0.f);
        hb [oc * 169] = r;
        hbb[oc * 169] = (bf16_t)r;      // same RNE cast the gemm used to do
    }
}

// x8-vectorized fp32 -> bf16 weight conversion (pad cols/rows zeroed).
__device__ void role_wb16v8(int blk, const float* __restrict__ src,
                            bf16_t* __restrict__ dst, int N, int K, int Kp, int totalv)
{
    const int idx = blk * 256 + threadIdx.x;     // one thread per 8-elem group
    if (idx >= totalv) return;
    const int kg = Kp >> 3;
    const int n  = idx / kg;
    const int k0 = (idx - n * kg) * 8;
    bf16x8 v;
#pragma unroll
    for (int i = 0; i < 8; ++i) {
        const int k = k0 + i;
        const float f = (n < N && k < K) ? src[(size_t)n * K + k] : 0.f;
        v[i] = (bf16_t)f;
    }
    *(bf16x8*)&dst[(size_t)n * Kp + k0] = v;
}

__device__ void role_w2t(int blk, const float* __restrict__ w2, float* __restrict__ w2p)
{
    const int idx = blk * 256 + threadIdx.x;
    if (idx >= 50 * 600) return;
    const int ic = idx / 600, r = idx % 600, oc = r / 12, j = r % 12;
    w2p[idx] = (j < 9) ? w2[oc * 450 + ic * 9 + j] : 0.f;
}

// conv2 (50->50) + relu + pool; Round-16: TWO images per block, thread =
// 5 oc x 1 pooled pos applied to both images (accA/accB). Weight b128
// reads amortize over 2 images' FMA bursts -> LDS issue traffic ~halved.
// in[2 buf][2 img][680] (10880 B) + wbuf[2][2400] (19200 B) = 30080 B.
// Per-output FP math identical to r11/r15: ic order 0..49, verbatim taps.
__device__ void role_conv2(char* smem, int blkpair,
    const float* __restrict__ h1, const float* __restrict__ w2p,
    const float* __restrict__ b2, float* __restrict__ h2,
    bf16_t* __restrict__ h2b)
{
    float* in   = (float*)smem;          // [2][2][680]
    float* wbuf = in + 2720;             // [2][2400], 16B-aligned (2720*4=10880)
    const int t  = threadIdx.x;
    const int b0 = blkpair * 2;
    const float* hA = h1 + (size_t)b0 * 8480;
    const float* hB = h1 + (size_t)(b0 + 1) * 8480;

    // stage chunk 0 (ic 0..3): both images' input + shared weights
    for (int s = t; s < 676; s += 256) {
        in[s]       = hA[s];
        in[680 + s] = hB[s];
    }
    {
        const float4* src = (const float4*)w2p;
        float4* dst = (float4*)wbuf;
        for (int s = t; s < 600; s += 256) dst[s] = src[s];
    }
    __syncthreads();
    if (t < 60) {
        const int img = t / 30, o = t - img * 30;
        h2 [(size_t)(b0 + img) * 1280 + 1250 + o] = 0.f;
        h2b[(size_t)(b0 + img) * 1280 + 1250 + o] = (bf16_t)0.f;
    }

    const int ocg = t / 25;
    const int pos = t % 25;
    const int py = pos / 5, px = pos % 5;
    const int oc0 = ocg * 5;
    const bool act = (t < 250);

    float accA[5][4], accB[5][4];
#pragma unroll
    for (int j = 0; j < 5; ++j)
#pragma unroll
        for (int q = 0; q < 4; ++q) { accA[j][q] = 0.f; accB[j][q] = 0.f; }

    for (int ic0 = 0; ic0 < 50; ic0 += 4) {
        const int cur = (ic0 >> 2) & 1;
        if (ic0 + 4 < 50) {           // prefetch next <=4-ic chunk (input+weights)
            const int nxt = cur ^ 1;
            const int nic2 = (50 - ic0 - 4 < 4) ? (50 - ic0 - 4) : 4;
            const size_t base = (size_t)(ic0 + 4) * 169;
            for (int s = t; s < nic2 * 169; s += 256) {
                in[nxt * 1360 + s]       = hA[base + s];
                in[nxt * 1360 + 680 + s] = hB[base + s];
            }
            const float4* src = (const float4*)(w2p + (size_t)(ic0 + 4) * 600);
            float4* dst = (float4*)(wbuf + nxt * 2400);
            for (int s = t; s < nic2 * 150; s += 256) dst[s] = src[s];
        }
        if (act) {
            const int nic = (50 - ic0 < 4) ? (50 - ic0) : 4;
            const float* ibcA = in + cur * 1360 + (2 * py) * 13 + 2 * px;
            for (int icl = 0; icl < nic; ++icl) {
                float pA[4][4], pB[4][4];
                const float* ipA = ibcA + icl * 169;
                const float* ipB = ipA + 680;
#pragma unroll
                for (int r = 0; r < 4; ++r)
#pragma unroll
                    for (int c = 0; c < 4; ++c) {
                        pA[r][c] = ipA[r * 13 + c];
                        pB[r][c] = ipB[r * 13 + c];
                    }
                const float* wl = wbuf + cur * 2400 + icl * 600 + oc0 * 12;
#pragma unroll
                for (int j = 0; j < 5; ++j) {
                    const f32x4 wv0 = *(const f32x4*)(wl + j * 12);
                    const f32x4 wv1 = *(const f32x4*)(wl + j * 12 + 4);
                    const f32x4 wv2 = *(const f32x4*)(wl + j * 12 + 8);
                    const float w00 = wv0[0], w01 = wv0[1], w02 = wv0[2];
                    const float w10 = wv0[3], w11 = wv1[0], w12 = wv1[1];
                    const float w20 = wv1[2], w21 = wv1[3], w22 = wv2[0];
#pragma unroll
                    for (int dy = 0; dy < 2; ++dy)
#pragma unroll
                        for (int dx = 0; dx < 2; ++dx) {
                            accA[j][dy * 2 + dx] +=
                                  pA[dy + 0][dx + 0] * w00 + pA[dy + 0][dx + 1] * w01 + pA[dy + 0][dx + 2] * w02
                                + pA[dy + 1][dx + 0] * w10 + pA[dy + 1][dx + 1] * w11 + pA[dy + 1][dx + 2] * w12
                                + pA[dy + 2][dx + 0] * w20 + pA[dy + 2][dx + 1] * w21 + pA[dy + 2][dx + 2] * w22;
                        }
#pragma unroll
                    for (int dy = 0; dy < 2; ++dy)
#pragma unroll
                        for (int dx = 0; dx < 2; ++dx) {
                            accB[j][dy * 2 + dx] +=
                                  pB[dy + 0][dx + 0] * w00 + pB[dy + 0][dx + 1] * w01 + pB[dy + 0][dx + 2] * w02
                                + pB[dy + 1][dx + 0] * w10 + pB[dy + 1][dx + 1] * w11 + pB[dy + 1][dx + 2] * w12
                                + pB[dy + 2][dx + 0] * w20 + pB[dy + 2][dx + 1] * w21 + pB[dy + 2][dx + 2] * w22;
                        }
                }
            }
        }
        __syncthreads();
    }

    if (act) {
#pragma unroll
        for (int j = 0; j < 5; ++j) {
            float vA = fmaxf(fmaxf(accA[j][0], accA[j][1]), fmaxf(accA[j][2], accA[j][3]));
            const float rA = fmaxf(vA + b2[oc0 + j], 0.f);
            h2 [(size_t)b0 * 1280 + (oc0 + j) * 25 + pos] = rA;
            h2b[(size_t)b0 * 1280 + (oc0 + j) * 25 + pos] = (bf16_t)rA;
            float vB = fmaxf(fmaxf(accB[j][0], accB[j][1]), fmaxf(accB[j][2], accB[j][3]));
            const float rB = fmaxf(vB + b2[oc0 + j], 0.f);
            h2 [(size_t)(b0 + 1) * 1280 + (oc0 + j) * 25 + pos] = rB;
            h2b[(size_t)(b0 + 1) * 1280 + (oc0 + j) * 25 + pos] = (bf16_t)rB;
        }
    }
}

// conv3 + relu + pool + FOLDED exit2. 4 img/block; wave il == image il,
// so exit2 is a pure shuffle reduce (no barrier, no LDS).
__device__ void role_conv3x(char* smem, int blk,
    const float* __restrict__ h2, const float* __restrict__ w3,
    const float* __restrict__ b3,
    const float* __restrict__ d2w, const float* __restrict__ d2b,
    int* __restrict__ e2, float* __restrict__ f3)
{
    float* in = (float*)smem;    // 5000
    const int t = threadIdx.x;
    for (int i = t; i < 5000; i += 256) {
        const int img = i / 1250, off = i % 1250;
        in[i] = h2[(size_t)(blk * 4 + img) * 1280 + off];
    }
    __syncthreads();
    const int il   = t >> 6;
    const int lane = t & 63;

    // folded exit2: one wave per image, strided dot + shuffle tree
    {
        const float* ip = &in[il * 1250];
        float s0 = 0.f, s1 = 0.f;
        for (int i = lane; i < 1250; i += 64) {
            const float vv = ip[i];
            s0 += vv * d2w[i];
            s1 += vv * d2w[1250 + i];
        }
#pragma unroll
        for (int off = 32; off > 0; off >>= 1) {
            s0 += __shfl_down(s0, off);
            s1 += __shfl_down(s1, off);
        }
        if (lane == 0) e2[blk * 4 + il] = (s0 + d2b[0] >= s1 + d2b[1]) ? 1 : 0;
    }

    const int oc = lane;
    if (oc >= 50) return;

    const float* ip0 = &in[il * 1250];
    float a00 = 0.f, a01 = 0.f, a10 = 0.f, a11 = 0.f;
    for (int ic = 0; ic < 50; ++ic) {
        float p[4][4];
        const float* ip = ip0 + ic * 25;
#pragma unroll
        for (int r = 0; r < 4; ++r)
#pragma unroll
            for (int c = 0; c < 4; ++c) p[r][c] = ip[r * 5 + c];
        const float* wp = &w3[((size_t)oc * 50 + ic) * 9];
        const float w00 = wp[0], w01 = wp[1], w02 = wp[2];
        const float w10 = wp[3], w11 = wp[4], w12 = wp[5];
        const float w20 = wp[6], w21 = wp[7], w22 = wp[8];
        a00 += p[0][0]*w00 + p[0][1]*w01 + p[0][2]*w02 + p[1][0]*w10 + p[1][1]*w11 + p[1][2]*w12 + p[2][0]*w20 + p[2][1]*w21 + p[2][2]*w22;
        a01 += p[0][1]*w00 + p[0][2]*w01 + p[0][3]*w02 + p[1][1]*w10 + p[1][2]*w11 + p[1][3]*w12 + p[2][1]*w20 + p[2][2]*w21 + p[2][3]*w22;
        a10 += p[1][0]*w00 + p[1][1]*w01 + p[1][2]*w02 + p[2][0]*w10 + p[2][1]*w11 + p[2][2]*w12 + p[3][0]*w20 + p[3][1]*w21 + p[3][2]*w22;
        a11 += p[1][1]*w00 + p[1][2]*w01 + p[1][3]*w02 + p[2][1]*w10 + p[2][2]*w11 + p[2][3]*w12 + p[3][1]*w20 + p[3][2]*w21 + p[3][3]*w22;
    }
    float v = fmaxf(fmaxf(a00, a01), fmaxf(a10, a11)) + b3[oc];
    f3[(size_t)(blk * 4 + il) * 50 + oc] = fmaxf(v, 0.f);
}

__device__ void role_exit(char* smem, int b,
    const float* __restrict__ F, int ldf, int K,
    const float* __restrict__ dw, const float* __restrict__ db, int* __restrict__ e)
{
    float* r0 = (float*)smem;   // 256
    float* r1 = r0 + 256;       // 256
    const int t = threadIdx.x;
    const float* f = F + (size_t)b * ldf;
    float s0 = 0.f, s1 = 0.f;
    for (int i = t; i < K; i += 256) {
        const float v = f[i];
        s0 += v * dw[i];
        s1 += v * dw[K + i];
    }
    r0[t] = s0; r1[t] = s1;
    __syncthreads();
    for (int s = 128; s > 0; s >>= 1) {
        if (t < s) { r0[t] += r0[t + s]; r1[t] += r1[t + s]; }
        __syncthreads();
    }
    if (t == 0) e[b] = (r0[0] + db[0] >= r1[0] + db[1]) ? 1 : 0;
}

// MFMA GEMM split-K=2 (r9-proven schedule). A is PRE-CONVERTED bf16
// (h1b/h2b): staging is a bare uint4 copy, no cvt chain, half the bytes.
__device__ void role_gemm(char* smem, int g,
    const bf16_t* __restrict__ A, int lda, const bf16_t* __restrict__ W,
    const float* __restrict__ bias, float* __restrict__ C0, float* __restrict__ C1,
    int Kp, int khalf, int Nout, int ldc)
{
    bf16_t* As = (bf16_t*)smem;      // 128*40
    bf16_t* Bs = As + 128 * 40;      // 64*40

    const int t = threadIdx.x;
    const int m0 = (g & 31) * 128;
    const int n0 = ((g >> 5) & 7) * 64;
    const int kz = g >> 8;
    const int kbeg = kz ? khalf : 0;
    const int kend = kz ? Kp : khalf;
    float* C = kz ? C1 : C0;

    const int wave = t >> 6;
    const int lane = t & 63;
    const int wm = (wave >> 1) * 64;
    const int wn = (wave & 1) * 32;
    const int quad = lane >> 4;
    const int lr = lane & 15;

    f32x4 acc[4][2];
#pragma unroll
    for (int i = 0; i < 4; ++i)
#pragma unroll
        for (int j = 0; j < 2; ++j) acc[i][j] = (f32x4)0.f;

    const int ar = t >> 2;
    const int ac = (t & 3) * 8;

    for (int k0 = kbeg; k0 < kend; k0 += 32) {
        __syncthreads();
#pragma unroll
        for (int h = 0; h < 2; ++h) {
            *(uint4*)&As[(ar + h * 64) * 40 + ac] =
                *(const uint4*)&A[(size_t)(m0 + ar + h * 64) * lda + k0 + ac];
        }
        *(uint4*)&Bs[ar * 40 + ac] = *(const uint4*)&W[(size_t)(n0 + ar) * Kp + k0 + ac];
        __syncthreads();

        bf16x8 af[4], bfr[2];
#pragma unroll
        for (int i = 0; i < 4; ++i)
            af[i] = *(const bf16x8*)&As[(wm + i * 16 + lr) * 40 + quad * 8];
#pragma unroll
        for (int j = 0; j < 2; ++j)
            bfr[j] = *(const bf16x8*)&Bs[(wn + j * 16 + lr) * 40 + quad * 8];
#pragma unroll
        for (int i = 0; i < 4; ++i)
#pragma unroll
            for (int j = 0; j < 2; ++j)
                acc[i][j] = __builtin_amdgcn_mfma_f32_16x16x32_bf16(af[i], bfr[j], acc[i][j], 0, 0, 0);
    }

#pragma unroll
    for (int j = 0; j < 2; ++j) {
        const int n = n0 + wn + j * 16 + lr;
        const float bv = (kz == 0 && n < Nout) ? bias[n] : 0.f;
#pragma unroll
        for (int i = 0; i < 4; ++i) {
            const int mrow = m0 + wm + i * 16 + quad * 4;
#pragma unroll
            for (int r = 0; r < 4; ++r)
                C[(size_t)(mrow + r) * ldc + n] = acc[i][j][r] + bv;
        }
    }
}

// lin10: out[b,o<10] = (U[+U2]) @ W^T + bias; 16 img x 16 k-strips per block.
__device__ void role_lin10(char* smem, int blk,
    const float* __restrict__ U, const float* __restrict__ U2, int ldu,
    const float* __restrict__ W, const float* __restrict__ bias,
    float* __restrict__ out)
{
    float* red = (float*)smem;   // [16][10][17]
    const int t = threadIdx.x;
    const int ks = t & 15;
    const int il = t >> 4;
    const int b  = blk * 16 + il;
    const float* u = U + (size_t)b * ldu;

    float acc[10];
#pragma unroll
    for (int o = 0; o < 10; ++o) acc[o] = 0.f;

    if (U2) {
        const float* u2 = U2 + (size_t)b * ldu;
        for (int i = 0; i < 31; ++i) {
            const int k = ks + i * 16;
            const float uv = u[k] + u2[k];
#pragma unroll
            for (int o = 0; o < 10; ++o) acc[o] += uv * W[o * 500 + k];
        }
        const int k = ks + 496;
        if (k < 500) {
            const float uv = u[k] + u2[k];
#pragma unroll
            for (int o = 0; o < 10; ++o) acc[o] += uv * W[o * 500 + k];
        }
    } else {
        for (int i = 0; i < 31; ++i) {
            const int k = ks + i * 16;
            const float uv = u[k];
#pragma unroll
            for (int o = 0; o < 10; ++o) acc[o] += uv * W[o * 500 + k];
        }
        const int k = ks + 496;
        if (k < 500) {
            const float uv = u[k];
#pragma unroll
            for (int o = 0; o < 10; ++o) acc[o] += uv * W[o * 500 + k];
        }
    }
#pragma unroll
    for (int o = 0; o < 10; ++o) red[(il * 10 + o) * 17 + ks] = acc[o];
    __syncthreads();
    if (t < 160) {
        const int il2 = t / 10, o = t - il2 * 10;
        float s = 0.f;
#pragma unroll
        for (int q = 0; q < 16; ++q) s += red[(il2 * 10 + o) * 17 + q];
        out[(size_t)(blk * 16 + il2) * 10 + o] = s + bias[o];
    }
}

// ============================ fused kernels ================================

__global__ __launch_bounds__(256) void k_prep(
    const float* x, const float* c1w, const float* c1b, float* h1, bf16_t* h1b,
    const float* l1c1w, bf16_t* Wb1, const float* l1c2w, bf16_t* Wb2,
    const float* c2w, float* w2p)
{
    extern __shared__ char smem[];
    const int g = blockIdx.x;
    if (g < 2704)        role_conv1(smem, g, x, c1w, c1b, h1, h1b);
    else if (g < 4824)   role_wb16v8(g - 2704, l1c1w, Wb1, 500, 8450, 8480, 512 * 1060);
    else if (g < 5144)   role_wb16v8(g - 4824, l1c2w, Wb2, 500, 1250, 1280, 512 * 160);
    else                 role_w2t(g - 5144, c2w, w2p);
}

__global__ __launch_bounds__(256) void k_stage1(
    const float* h1, const bf16_t* h1b, const bf16_t* Wb1, const float* l1c1b,
    float* u, float* up,
    const float* d1w, const float* d1b, int* e1,
    const float* w2p, const float* c2b, float* h2, bf16_t* h2b)
{
    extern __shared__ char smem[];
    const int g = blockIdx.x;
    if (g < 512)         role_gemm(smem, g, h1b, 8480, Wb1, l1c1b, u, up, 8480, 4256, 500, 512);
    else if (g < 2560)   role_conv2(smem, g - 512, h1, w2p, c2b, h2, h2b);
    else                 role_exit(smem, g - 2560, h1, 8480, 8450, d1w, d1b, e1);
}

__global__ __launch_bounds__(256) void k_stage2(
    const float* h2, const bf16_t* h2b, const bf16_t* Wb2, const float* l1c2b,
    float* v, float* vp,
    const float* d2w, const float* d2b, int* e2,
    const float* c3w, const float* c3b, float* f3,
    const float* u, const float* up, const float* l2c1w, const float* l2c1b, float* out1)
{
    extern __shared__ char smem[];
    const int g = blockIdx.x;
    if (g < 512)         role_gemm(smem, g, h2b, 1280, Wb2, l1c2b, v, vp, 1280, 640, 500, 512);
    else if (g < 1536)   role_conv3x(smem, g - 512, h2, c3w, c3b, d2w, d2b, e2, f3);
    else                 role_lin10(smem, g - 1536, u, up, 512, l2c1w, l2c1b, out1);
}

// k_tail: per block = 16 samples. lin10-2 (v/vp) -> o2loc; lin500 -> u3 LDS;
// lin10-3 (u3 LDS) -> o3loc; select + log_softmax -> out. FP per-(b,o)
// expressions identical to round 10's separate kernels.
__global__ __launch_bounds__(256) void k_tail(
    const float* __restrict__ v, const float* __restrict__ vp,
    const float* __restrict__ l2c2w, const float* __restrict__ l2c2b,
    const float* __restrict__ f3, const float* __restrict__ l1w, const float* __restrict__ l1b,
    const float* __restrict__ l2w, const float* __restrict__ l2b,
    const float* __restrict__ out1, const int* __restrict__ e1, const int* __restrict__ e2,
    float* __restrict__ out)
{
    __shared__ float fs[800];        // 16 x 50
    __shared__ float u3loc[8000];    // 16 x 500
    __shared__ float red[2720];      // 16 x 10 x 17
    __shared__ float o2loc[160];
    __shared__ float o3loc[160];

    const int t   = threadIdx.x;
    const int blk = blockIdx.x;
    const int ks  = t & 15;
    const int il  = t >> 4;

    // stage f3 for 16 images
    for (int i = t; i < 800; i += 256) fs[i] = f3[(size_t)blk * 800 + i];
    __syncthreads();

    // lin500 -> u3loc (same per-(b,o) expression as round 10's role_lin500)
    for (int im = 0; im < 16; ++im) {
        for (int o = t; o < 500; o += 256) {
            float s = 0.f;
#pragma unroll
            for (int k = 0; k < 50; ++k) s += fs[im * 50 + k] * l1w[o * 50 + k];
            u3loc[im * 500 + o] = fmaxf(s + l1b[o], 0.f);
        }
    }

    // lin10-2 from v/vp (global, ldu=512)
    {
        const float* uu  = v  + (size_t)(blk * 16 + il) * 512;
        const float* uu2 = vp + (size_t)(blk * 16 + il) * 512;
        float acc[10];
#pragma unroll
        for (int o = 0; o < 10; ++o) acc[o] = 0.f;
        for (int i = 0; i < 31; ++i) {
            const int k = ks + i * 16;
            const float uv = uu[k] + uu2[k];
#pragma unroll
            for (int o = 0; o < 10; ++o) acc[o] += uv * l2c2w[o * 500 + k];
        }
        const int k = ks + 496;
        if (k < 500) {
            const float uv = uu[k] + uu2[k];
#pragma unroll
            for (int o = 0; o < 10; ++o) acc[o] += uv * l2c2w[o * 500 + k];
        }
        __syncthreads();   // u3loc writes done; red free to use
#pragma unroll
        for (int o = 0; o < 10; ++o) red[(il * 10 + o) * 17 + ks] = acc[o];
        __syncthreads();
        if (t < 160) {
            const int il2 = t / 10, o = t - il2 * 10;
            float s = 0.f;
#pragma unroll
            for (int q = 0; q < 16; ++q) s += red[(il2 * 10 + o) * 17 + q];
            o2loc[t] = s + l2c2b[o];
        }
        __syncthreads();
    }

    // lin10-3 from u3loc (LDS, ldu=500)
    {
        const float* uu = u3loc + il * 500;
        float acc[10];
#pragma unroll
        for (int o = 0; o < 10; ++o) acc[o] = 0.f;
        for (int i = 0; i < 31; ++i) {
            const int k = ks + i * 16;
            const float uv = uu[k];
#pragma unroll
            for (int o = 0; o < 10; ++o) acc[o] += uv * l2w[o * 500 + k];
        }
        const int k = ks + 496;
        if (k < 500) {
            const float uv = uu[k];
#pragma unroll
            for (int o = 0; o < 10; ++o) acc[o] += uv * l2w[o * 500 + k];
        }
#pragma unroll
        for (int o = 0; o < 10; ++o) red[(il * 10 + o) * 17 + ks] = acc[o];
        __syncthreads();
        if (t < 160) {
            const int il2 = t / 10, o = t - il2 * 10;
            float s = 0.f;
#pragma unroll
            for (int q = 0; q < 16; ++q) s += red[(il2 * 10 + o) * 17 + q];
            o3loc[t] = s + l2b[o];
        }
        __syncthreads();
    }

    // select + log_softmax (one thread per sample)
    if (t < 16) {
        const int b = blk * 16 + t;
        float vv[10];
        if (e1[b]) {
            const float* src = out1 + (size_t)b * 10;
#pragma unroll
            for (int o = 0; o < 10; ++o) vv[o] = src[o];
        } else if (e2[b]) {
#pragma unroll
            for (int o = 0; o < 10; ++o) vv[o] = o2loc[t * 10 + o];
        } else {
#pragma unroll
            for (int o = 0; o < 10; ++o) vv[o] = o3loc[t * 10 + o];
        }
        float m = -3.4e38f;
#pragma unroll
        for (int o = 0; o < 10; ++o) m = fmaxf(m, vv[o]);
        float s = 0.f;
#pragma unroll
        for (int o = 0; o < 10; ++o) s += expf(vv[o] - m);
        const float ls = logf(s);
#pragma unroll
        for (int o = 0; o < 10; ++o) out[(size_t)b * 10 + o] = vv[o] - m - ls;
    }
}

// ---------------------------------------------------------------------------
static inline size_t align256(size_t v) { return (v + 255) & ~(size_t)255; }

extern "C" void kernel_launch(void* const* d_in, const int* in_sizes, int n_in,
                              void* d_out, int out_size, void* d_ws, size_t ws_size,
                              hipStream_t stream)
{
    const float* x     = (const float*)d_in[0];
    const float* c1w   = (const float*)d_in[1];
    const float* c1b   = (const float*)d_in[2];
    const float* c2w   = (const float*)d_in[3];
    const float* c2b   = (const float*)d_in[4];
    const float* c3w   = (const float*)d_in[5];
    const float* c3b   = (const float*)d_in[6];
    const float* l1c1w = (const float*)d_in[7];
    const float* l1c1b = (const float*)d_in[8];
    const float* l2c1w = (const float*)d_in[9];
    const float* l2c1b = (const float*)d_in[10];
    const float* l1c2w = (const float*)d_in[11];
    const float* l1c2b = (const float*)d_in[12];
    const float* l2c2w = (const float*)d_in[13];
    const float* l2c2b = (const float*)d_in[14];
    const float* l1w   = (const float*)d_in[15];
    const float* l1b   = (const float*)d_in[16];
    const float* l2w   = (const float*)d_in[17];
    const float* l2b   = (const float*)d_in[18];
    const float* d1w   = (const float*)d_in[19];
    const float* d1b   = (const float*)d_in[20];
    const float* d2w   = (const float*)d_in[21];
    const float* d2b   = (const float*)d_in[22];

    // ---- workspace layout (single chunk, B=4096)
    size_t off = 0;
    const size_t oWb1  = off; off = align256(off + (size_t)512 * 8480 * 2);
    const size_t oWb2  = off; off = align256(off + (size_t)512 * 1280 * 2);
    const size_t oW2P  = off; off = align256(off + (size_t)50 * 600 * 4);
    const size_t oOut1 = off; off = align256(off + (size_t)B_IMG * 10 * 4);
    const size_t oE1   = off; off = align256(off + (size_t)B_IMG * 4);
    const size_t oE2   = off; off = align256(off + (size_t)B_IMG * 4);
    const size_t oH1   = off; off = align256(off + (size_t)B_IMG * 8480 * 4);
    const size_t oH2   = off; off = align256(off + (size_t)B_IMG * 1280 * 4);
    const size_t oU    = off; off = align256(off + (size_t)B_IMG * 512 * 4);
    const size_t oUP   = off; off = align256(off + (size_t)B_IMG * 512 * 4);
    const size_t oF3   = off; off = align256(off + (size_t)B_IMG * 50 * 4);
    const size_t oH1B  = off; off = align256(off + (size_t)B_IMG * 8480 * 2);
    const size_t oH2B  = off; off = align256(off + (size_t)B_IMG * 1280 * 2);

    char* ws = (char*)d_ws;
    bf16_t* Wb1  = (bf16_t*)(ws + oWb1);
    bf16_t* Wb2  = (bf16_t*)(ws + oWb2);
    float*  w2p  = (float*) (ws + oW2P);
    float*  out1 = (float*) (ws + oOut1);
    int*    e1   = (int*)   (ws + oE1);
    int*    e2   = (int*)   (ws + oE2);
    float*  h1   = (float*) (ws + oH1);
    float*  h2   = (float*) (ws + oH2);
    float*  u    = (float*) (ws + oU);
    float*  up   = (float*) (ws + oUP);
    float*  f3   = (float*) (ws + oF3);
    bf16_t* h1b  = (bf16_t*)(ws + oH1B);
    bf16_t* h2b  = (bf16_t*)(ws + oH2B);
    // stage-2 gemm outputs carved from the dead h1 region
    float*  v    = h1;                          // 4096*512 f32
    float*  vp   = h1 + (size_t)B_IMG * 512;    // 4096*512 f32

    float* out = (float*)d_out;

    // P: conv1 (+h1b mirror) + weight conversions (all independent)
    k_prep<<<5262, 256, 2048, stream>>>(x, c1w, c1b, h1, h1b,
                                        l1c1w, Wb1, l1c2w, Wb2, c2w, w2p);
    // A: gemm1(h1b) | conv2 x2-img (+h2b) | exit1; LDS 30080 (conv2 shape)
    k_stage1<<<6656, 256, 30080, stream>>>(h1, h1b, Wb1, l1c1b, u, up,
                                           d1w, d1b, e1, w2p, c2b, h2, h2b);
    // C: gemm2(h2b) | conv3+exit2 | lin10-1  (consume h2/h2b, stage1-u)
    k_stage2<<<1792, 256, 20000, stream>>>(h2, h2b, Wb2, l1c2b, v, vp, d2w, d2b, e2,
                                           c3w, c3b, f3, u, up, l2c1w, l2c1b, out1);
    // T: lin10-2 | lin500 | lin10-3 | select  (per-16-sample blocks)
    k_tail<<<256, 256, 0, stream>>>(v, vp, l2c2w, l2c2b, f3, l1w, l1b, l2w, l2b,
                                    out1, e1, e2, out);

    (void)in_sizes; (void)n_in; (void)out_size; (void)ws_size;
}

// Round 6
// 652.995 us; speedup vs baseline: 1.1972x; 1.1972x over previous
//
#include <hip/hip_runtime.h>
#include <hip/hip_bf16.h>
#include <cstdint>

// ---------------------------------------------------------------------------
// ThreeLayerCNN (BranchyNet early-exit), B=4096.
// Precision: conv1/conv2/exit1/exit2 fp32 (argmax parity with numpy ref);
// big FC GEMMs (l1c1, l1c2) bf16 MFMA w/ fp32 accum (output tol 0.146).
// Round 17 (r16 post-mortem: LDS-traffic cut made it SLOWER because block
// count/occupancy fell -- stage1 wants many small blocks. Pattern: grid
// 8704->465us, 6656->527, 4608->543):
//  - FULL revert to r15 structure (712us best): 4096 1-img conv2 blocks,
//    LDS 24832, grid 8704, bf16 mirrors h1b/h2b, wb16v8, conv3x fold.
//  - ONE change: conv2 thread remap (ocg,pos)->(oc,py). Same 250 threads,
//    same LDS layout/staging/barriers. Per thread-ic: weights 15 b128 ->
//    3 b128 (one oc), inputs 16 b32 -> 52 b32 (4 rows x 13 cols, read2-
//    fusable, register-reused across 5 pooled px). Wave-ic LDS cycles
//    ~273 -> ~192. h2 BIT-IDENTICAL: verbatim 9-term taps via
//    p[r][c] == row[r][2px+c], ic order 0..49, same epilogue.
//  - Pre-commit: if stage1 in [455,475], conv2 inner loop is latency-
//    bound, not issue-bound -> stop touching it.
// ---------------------------------------------------------------------------

typedef __bf16 bf16_t;
typedef __bf16 bf16x8 __attribute__((ext_vector_type(8)));
typedef float  f32x4  __attribute__((ext_vector_type(4)));

#define B_IMG 4096

// ======================= role bodies (device functions) =====================

__device__ void role_conv1(char* smem, int blk,
    const float* __restrict__ x, const float* __restrict__ w1,
    const float* __restrict__ b1, float* __restrict__ h1,
    bf16_t* __restrict__ h1b)
{
    float* ws = (float*)smem;        // 450
    float* bs = ws + 456;            // 50
    const int t = threadIdx.x;
    for (int i = t; i < 450; i += 256) ws[i] = w1[i];
    if (t < 50) bs[t] = b1[t];
    __syncthreads();

    const int idx = blk * 256 + t;
    if (idx >= B_IMG * 169) return;
    const int b   = idx / 169;
    const int pos = idx % 169;
    const int py = pos / 13, px = pos % 13;

    const float* xp = x + (size_t)b * 784 + (2 * py) * 28 + 2 * px;
    float p[4][4];
#pragma unroll
    for (int r = 0; r < 4; ++r)
#pragma unroll
        for (int c = 0; c < 4; ++c) p[r][c] = xp[r * 28 + c];

    float*  hb  = h1  + (size_t)b * 8480 + pos;
    bf16_t* hbb = h1b + (size_t)b * 8480 + pos;
    if (pos < 30) {
        h1 [(size_t)b * 8480 + 8450 + pos] = 0.f;            // zero pad cols
        h1b[(size_t)b * 8480 + 8450 + pos] = (bf16_t)0.f;
    }

    for (int oc = 0; oc < 50; ++oc) {
        const float* wp = &ws[oc * 9];
        const float w00 = wp[0], w01 = wp[1], w02 = wp[2];
        const float w10 = wp[3], w11 = wp[4], w12 = wp[5];
        const float w20 = wp[6], w21 = wp[7], w22 = wp[8];
        float a[2][2];
#pragma unroll
        for (int dy = 0; dy < 2; ++dy)
#pragma unroll
            for (int dx = 0; dx < 2; ++dx) {
                a[dy][dx] = p[dy + 0][dx + 0] * w00 + p[dy + 0][dx + 1] * w01 + p[dy + 0][dx + 2] * w02
                          + p[dy + 1][dx + 0] * w10 + p[dy + 1][dx + 1] * w11 + p[dy + 1][dx + 2] * w12
                          + p[dy + 2][dx + 0] * w20 + p[dy + 2][dx + 1] * w21 + p[dy + 2][dx + 2] * w22;
            }
        float v = fmaxf(fmaxf(a[0][0], a[0][1]), fmaxf(a[1][0], a[1][1])) + bs[oc];
        const float r = fmaxf(v, 0.f);
        hb [oc * 169] = r;
        hbb[oc * 169] = (bf16_t)r;      // same RNE cast the gemm used to do
    }
}

// x8-vectorized fp32 -> bf16 weight conversion (pad cols/rows zeroed).
__device__ void role_wb16v8(int blk, const float* __restrict__ src,
                            bf16_t* __restrict__ dst, int N, int K, int Kp, int totalv)
{
    const int idx = blk * 256 + threadIdx.x;     // one thread per 8-elem group
    if (idx >= totalv) return;
    const int kg = Kp >> 3;
    const int n  = idx / kg;
    const int k0 = (idx - n * kg) * 8;
    bf16x8 v;
#pragma unroll
    for (int i = 0; i < 8; ++i) {
        const int k = k0 + i;
        const float f = (n < N && k < K) ? src[(size_t)n * K + k] : 0.f;
        v[i] = (bf16_t)f;
    }
    *(bf16x8*)&dst[(size_t)n * Kp + k0] = v;
}

__device__ void role_w2t(int blk, const float* __restrict__ w2, float* __restrict__ w2p)
{
    const int idx = blk * 256 + threadIdx.x;
    if (idx >= 50 * 600) return;
    const int ic = idx / 600, r = idx % 600, oc = r / 12, j = r % 12;
    w2p[idx] = (j < 9) ? w2[oc * 450 + ic * 9 + j] : 0.f;
}

// conv2 (50->50) + relu + pool; block per image. Round-17 thread remap:
// thread = (oc = t/5, py = t%5), computes one pool ROW (5 px) of one oc.
// Per ic: 4 input rows x 13 cols -> registers (reused across 5 px),
// 3 b128 weight reads (one oc). Staging/LDS/barriers byte-identical r15.
// Per-output FP: verbatim 9-term taps (p[r][c] == row[r][2px+c]),
// ic order 0..49 -> h2 bit-identical -> exit2 argmax parity.
__device__ void role_conv2(char* smem, int b,
    const float* __restrict__ h1, const float* __restrict__ w2p,
    const float* __restrict__ b2, float* __restrict__ h2,
    bf16_t* __restrict__ h2b)
{
    float* in   = (float*)smem;          // [2][680]
    float* wbuf = in + 1360;             // [2][2400], 16B-aligned (1360*4=5440)
    const int t = threadIdx.x;

    // stage chunk 0 (ic 0..3): input + weights
    for (int s = t; s < 676; s += 256) in[s] = h1[(size_t)b * 8480 + s];
    {
        const float4* src = (const float4*)w2p;
        float4* dst = (float4*)wbuf;
        for (int s = t; s < 600; s += 256) dst[s] = src[s];
    }
    __syncthreads();
    if (t < 30) {
        h2 [(size_t)b * 1280 + 1250 + t] = 0.f;
        h2b[(size_t)b * 1280 + 1250 + t] = (bf16_t)0.f;
    }

    const int oc = t / 5;                // 0..49 (wave: 13 distinct oc)
    const int py = t % 5;                // 0..4  (5-lane broadcast groups)
    const bool act = (t < 250);

    float acc[5][4];                     // [px][quad]
#pragma unroll
    for (int j = 0; j < 5; ++j)
#pragma unroll
        for (int q = 0; q < 4; ++q) acc[j][q] = 0.f;

    for (int ic0 = 0; ic0 < 50; ic0 += 4) {
        const int cur = (ic0 >> 2) & 1;
        if (ic0 + 4 < 50) {           // prefetch next <=4-ic chunk (input+weights)
            const int nxt = cur ^ 1;
            const int nic2 = (50 - ic0 - 4 < 4) ? (50 - ic0 - 4) : 4;
            for (int s = t; s < nic2 * 169; s += 256)
                in[nxt * 680 + s] = h1[(size_t)b * 8480 + (ic0 + 4) * 169 + s];
            const float4* src = (const float4*)(w2p + (size_t)(ic0 + 4) * 600);
            float4* dst = (float4*)(wbuf + nxt * 2400);
            for (int s = t; s < nic2 * 150; s += 256) dst[s] = src[s];
        }
        if (act) {
            const int nic = (50 - ic0 < 4) ? (50 - ic0) : 4;
            const float* ibc = in + cur * 680 + (2 * py) * 13;     // row base
            const float* wcb = wbuf + cur * 2400 + oc * 12;
            for (int icl = 0; icl < nic; ++icl) {
                float row[4][13];
                const float* ip = ibc + icl * 169;
#pragma unroll
                for (int r = 0; r < 4; ++r)
#pragma unroll
                    for (int c = 0; c < 13; ++c) row[r][c] = ip[r * 13 + c];
                const float* wl = wcb + icl * 600;
                const f32x4 wv0 = *(const f32x4*)(wl);
                const f32x4 wv1 = *(const f32x4*)(wl + 4);
                const f32x4 wv2 = *(const f32x4*)(wl + 8);
                const float w00 = wv0[0], w01 = wv0[1], w02 = wv0[2];
                const float w10 = wv0[3], w11 = wv1[0], w12 = wv1[1];
                const float w20 = wv1[2], w21 = wv1[3], w22 = wv2[0];
#pragma unroll
                for (int px = 0; px < 5; ++px) {
                    const int c0 = 2 * px;
#pragma unroll
                    for (int dy = 0; dy < 2; ++dy)
#pragma unroll
                        for (int dx = 0; dx < 2; ++dx) {
                            acc[px][dy * 2 + dx] +=
                                  row[dy + 0][c0 + dx + 0] * w00 + row[dy + 0][c0 + dx + 1] * w01 + row[dy + 0][c0 + dx + 2] * w02
                                + row[dy + 1][c0 + dx + 0] * w10 + row[dy + 1][c0 + dx + 1] * w11 + row[dy + 1][c0 + dx + 2] * w12
                                + row[dy + 2][c0 + dx + 0] * w20 + row[dy + 2][c0 + dx + 1] * w21 + row[dy + 2][c0 + dx + 2] * w22;
                        }
                }
            }
        }
        __syncthreads();
    }

    if (act) {
#pragma unroll
        for (int px = 0; px < 5; ++px) {
            float v = fmaxf(fmaxf(acc[px][0], acc[px][1]), fmaxf(acc[px][2], acc[px][3]));
            const float r = fmaxf(v + b2[oc], 0.f);
            h2 [(size_t)b * 1280 + oc * 25 + py * 5 + px] = r;
            h2b[(size_t)b * 1280 + oc * 25 + py * 5 + px] = (bf16_t)r;
        }
    }
}

// conv3 + relu + pool + FOLDED exit2. 4 img/block; wave il == image il,
// so exit2 is a pure shuffle reduce (no barrier, no LDS).
__device__ void role_conv3x(char* smem, int blk,
    const float* __restrict__ h2, const float* __restrict__ w3,
    const float* __restrict__ b3,
    const float* __restrict__ d2w, const float* __restrict__ d2b,
    int* __restrict__ e2, float* __restrict__ f3)
{
    float* in = (float*)smem;    // 5000
    const int t = threadIdx.x;
    for (int i = t; i < 5000; i += 256) {
        const int img = i / 1250, off = i % 1250;
        in[i] = h2[(size_t)(blk * 4 + img) * 1280 + off];
    }
    __syncthreads();
    const int il   = t >> 6;
    const int lane = t & 63;

    // folded exit2: one wave per image, strided dot + shuffle tree
    {
        const float* ip = &in[il * 1250];
        float s0 = 0.f, s1 = 0.f;
        for (int i = lane; i < 1250; i += 64) {
            const float vv = ip[i];
            s0 += vv * d2w[i];
            s1 += vv * d2w[1250 + i];
        }
#pragma unroll
        for (int off = 32; off > 0; off >>= 1) {
            s0 += __shfl_down(s0, off);
            s1 += __shfl_down(s1, off);
        }
        if (lane == 0) e2[blk * 4 + il] = (s0 + d2b[0] >= s1 + d2b[1]) ? 1 : 0;
    }

    const int oc = lane;
    if (oc >= 50) return;

    const float* ip0 = &in[il * 1250];
    float a00 = 0.f, a01 = 0.f, a10 = 0.f, a11 = 0.f;
    for (int ic = 0; ic < 50; ++ic) {
        float p[4][4];
        const float* ip = ip0 + ic * 25;
#pragma unroll
        for (int r = 0; r < 4; ++r)
#pragma unroll
            for (int c = 0; c < 4; ++c) p[r][c] = ip[r * 5 + c];
        const float* wp = &w3[((size_t)oc * 50 + ic) * 9];
        const float w00 = wp[0], w01 = wp[1], w02 = wp[2];
        const float w10 = wp[3], w11 = wp[4], w12 = wp[5];
        const float w20 = wp[6], w21 = wp[7], w22 = wp[8];
        a00 += p[0][0]*w00 + p[0][1]*w01 + p[0][2]*w02 + p[1][0]*w10 + p[1][1]*w11 + p[1][2]*w12 + p[2][0]*w20 + p[2][1]*w21 + p[2][2]*w22;
        a01 += p[0][1]*w00 + p[0][2]*w01 + p[0][3]*w02 + p[1][1]*w10 + p[1][2]*w11 + p[1][3]*w12 + p[2][1]*w20 + p[2][2]*w21 + p[2][3]*w22;
        a10 += p[1][0]*w00 + p[1][1]*w01 + p[1][2]*w02 + p[2][0]*w10 + p[2][1]*w11 + p[2][2]*w12 + p[3][0]*w20 + p[3][1]*w21 + p[3][2]*w22;
        a11 += p[1][1]*w00 + p[1][2]*w01 + p[1][3]*w02 + p[2][1]*w10 + p[2][2]*w11 + p[2][3]*w12 + p[3][1]*w20 + p[3][2]*w21 + p[3][3]*w22;
    }
    float v = fmaxf(fmaxf(a00, a01), fmaxf(a10, a11)) + b3[oc];
    f3[(size_t)(blk * 4 + il) * 50 + oc] = fmaxf(v, 0.f);
}

__device__ void role_exit(char* smem, int b,
    const float* __restrict__ F, int ldf, int K,
    const float* __restrict__ dw, const float* __restrict__ db, int* __restrict__ e)
{
    float* r0 = (float*)smem;   // 256
    float* r1 = r0 + 256;       // 256
    const int t = threadIdx.x;
    const float* f = F + (size_t)b * ldf;
    float s0 = 0.f, s1 = 0.f;
    for (int i = t; i < K; i += 256) {
        const float v = f[i];
        s0 += v * dw[i];
        s1 += v * dw[K + i];
    }
    r0[t] = s0; r1[t] = s1;
    __syncthreads();
    for (int s = 128; s > 0; s >>= 1) {
        if (t < s) { r0[t] += r0[t + s]; r1[t] += r1[t + s]; }
        __syncthreads();
    }
    if (t == 0) e[b] = (r0[0] + db[0] >= r1[0] + db[1]) ? 1 : 0;
}

// MFMA GEMM split-K=2 (r9-proven schedule). A is PRE-CONVERTED bf16
// (h1b/h2b): staging is a bare uint4 copy, no cvt chain, half the bytes.
__device__ void role_gemm(char* smem, int g,
    const bf16_t* __restrict__ A, int lda, const bf16_t* __restrict__ W,
    const float* __restrict__ bias, float* __restrict__ C0, float* __restrict__ C1,
    int Kp, int khalf, int Nout, int ldc)
{
    bf16_t* As = (bf16_t*)smem;      // 128*40
    bf16_t* Bs = As + 128 * 40;      // 64*40

    const int t = threadIdx.x;
    const int m0 = (g & 31) * 128;
    const int n0 = ((g >> 5) & 7) * 64;
    const int kz = g >> 8;
    const int kbeg = kz ? khalf : 0;
    const int kend = kz ? Kp : khalf;
    float* C = kz ? C1 : C0;

    const int wave = t >> 6;
    const int lane = t & 63;
    const int wm = (wave >> 1) * 64;
    const int wn = (wave & 1) * 32;
    const int quad = lane >> 4;
    const int lr = lane & 15;

    f32x4 acc[4][2];
#pragma unroll
    for (int i = 0; i < 4; ++i)
#pragma unroll
        for (int j = 0; j < 2; ++j) acc[i][j] = (f32x4)0.f;

    const int ar = t >> 2;
    const int ac = (t & 3) * 8;

    for (int k0 = kbeg; k0 < kend; k0 += 32) {
        __syncthreads();
#pragma unroll
        for (int h = 0; h < 2; ++h) {
            *(uint4*)&As[(ar + h * 64) * 40 + ac] =
                *(const uint4*)&A[(size_t)(m0 + ar + h * 64) * lda + k0 + ac];
        }
        *(uint4*)&Bs[ar * 40 + ac] = *(const uint4*)&W[(size_t)(n0 + ar) * Kp + k0 + ac];
        __syncthreads();

        bf16x8 af[4], bfr[2];
#pragma unroll
        for (int i = 0; i < 4; ++i)
            af[i] = *(const bf16x8*)&As[(wm + i * 16 + lr) * 40 + quad * 8];
#pragma unroll
        for (int j = 0; j < 2; ++j)
            bfr[j] = *(const bf16x8*)&Bs[(wn + j * 16 + lr) * 40 + quad * 8];
#pragma unroll
        for (int i = 0; i < 4; ++i)
#pragma unroll
            for (int j = 0; j < 2; ++j)
                acc[i][j] = __builtin_amdgcn_mfma_f32_16x16x32_bf16(af[i], bfr[j], acc[i][j], 0, 0, 0);
    }

#pragma unroll
    for (int j = 0; j < 2; ++j) {
        const int n = n0 + wn + j * 16 + lr;
        const float bv = (kz == 0 && n < Nout) ? bias[n] : 0.f;
#pragma unroll
        for (int i = 0; i < 4; ++i) {
            const int mrow = m0 + wm + i * 16 + quad * 4;
#pragma unroll
            for (int r = 0; r < 4; ++r)
                C[(size_t)(mrow + r) * ldc + n] = acc[i][j][r] + bv;
        }
    }
}

// lin10: out[b,o<10] = (U[+U2]) @ W^T + bias; 16 img x 16 k-strips per block.
__device__ void role_lin10(char* smem, int blk,
    const float* __restrict__ U, const float* __restrict__ U2, int ldu,
    const float* __restrict__ W, const float* __restrict__ bias,
    float* __restrict__ out)
{
    float* red = (float*)smem;   // [16][10][17]
    const int t = threadIdx.x;
    const int ks = t & 15;
    const int il = t >> 4;
    const int b  = blk * 16 + il;
    const float* u = U + (size_t)b * ldu;

    float acc[10];
#pragma unroll
    for (int o = 0; o < 10; ++o) acc[o] = 0.f;

    if (U2) {
        const float* u2 = U2 + (size_t)b * ldu;
        for (int i = 0; i < 31; ++i) {
            const int k = ks + i * 16;
            const float uv = u[k] + u2[k];
#pragma unroll
            for (int o = 0; o < 10; ++o) acc[o] += uv * W[o * 500 + k];
        }
        const int k = ks + 496;
        if (k < 500) {
            const float uv = u[k] + u2[k];
#pragma unroll
            for (int o = 0; o < 10; ++o) acc[o] += uv * W[o * 500 + k];
        }
    } else {
        for (int i = 0; i < 31; ++i) {
            const int k = ks + i * 16;
            const float uv = u[k];
#pragma unroll
            for (int o = 0; o < 10; ++o) acc[o] += uv * W[o * 500 + k];
        }
        const int k = ks + 496;
        if (k < 500) {
            const float uv = u[k];
#pragma unroll
            for (int o = 0; o < 10; ++o) acc[o] += uv * W[o * 500 + k];
        }
    }
#pragma unroll
    for (int o = 0; o < 10; ++o) red[(il * 10 + o) * 17 + ks] = acc[o];
    __syncthreads();
    if (t < 160) {
        const int il2 = t / 10, o = t - il2 * 10;
        float s = 0.f;
#pragma unroll
        for (int q = 0; q < 16; ++q) s += red[(il2 * 10 + o) * 17 + q];
        out[(size_t)(blk * 16 + il2) * 10 + o] = s + bias[o];
    }
}

// ============================ fused kernels ================================

__global__ __launch_bounds__(256) void k_prep(
    const float* x, const float* c1w, const float* c1b, float* h1, bf16_t* h1b,
    const float* l1c1w, bf16_t* Wb1, const float* l1c2w, bf16_t* Wb2,
    const float* c2w, float* w2p)
{
    extern __shared__ char smem[];
    const int g = blockIdx.x;
    if (g < 2704)        role_conv1(smem, g, x, c1w, c1b, h1, h1b);
    else if (g < 4824)   role_wb16v8(g - 2704, l1c1w, Wb1, 500, 8450, 8480, 512 * 1060);
    else if (g < 5144)   role_wb16v8(g - 4824, l1c2w, Wb2, 500, 1250, 1280, 512 * 160);
    else                 role_w2t(g - 5144, c2w, w2p);
}

__global__ __launch_bounds__(256) void k_stage1(
    const float* h1, const bf16_t* h1b, const bf16_t* Wb1, const float* l1c1b,
    float* u, float* up,
    const float* d1w, const float* d1b, int* e1,
    const float* w2p, const float* c2b, float* h2, bf16_t* h2b)
{
    extern __shared__ char smem[];
    const int g = blockIdx.x;
    if (g < 512)         role_gemm(smem, g, h1b, 8480, Wb1, l1c1b, u, up, 8480, 4256, 500, 512);
    else if (g < 4608)   role_conv2(smem, g - 512, h1, w2p, c2b, h2, h2b);
    else                 role_exit(smem, g - 4608, h1, 8480, 8450, d1w, d1b, e1);
}

__global__ __launch_bounds__(256) void k_stage2(
    const float* h2, const bf16_t* h2b, const bf16_t* Wb2, const float* l1c2b,
    float* v, float* vp,
    const float* d2w, const float* d2b, int* e2,
    const float* c3w, const float* c3b, float* f3,
    const float* u, const float* up, const float* l2c1w, const float* l2c1b, float* out1)
{
    extern __shared__ char smem[];
    const int g = blockIdx.x;
    if (g < 512)         role_gemm(smem, g, h2b, 1280, Wb2, l1c2b, v, vp, 1280, 640, 500, 512);
    else if (g < 1536)   role_conv3x(smem, g - 512, h2, c3w, c3b, d2w, d2b, e2, f3);
    else                 role_lin10(smem, g - 1536, u, up, 512, l2c1w, l2c1b, out1);
}

// k_tail: per block = 16 samples. lin10-2 (v/vp) -> o2loc; lin500 -> u3 LDS;
// lin10-3 (u3 LDS) -> o3loc; select + log_softmax -> out. FP per-(b,o)
// expressions identical to round 10's separate kernels.
__global__ __launch_bounds__(256) void k_tail(
    const float* __restrict__ v, const float* __restrict__ vp,
    const float* __restrict__ l2c2w, const float* __restrict__ l2c2b,
    const float* __restrict__ f3, const float* __restrict__ l1w, const float* __restrict__ l1b,
    const float* __restrict__ l2w, const float* __restrict__ l2b,
    const float* __restrict__ out1, const int* __restrict__ e1, const int* __restrict__ e2,
    float* __restrict__ out)
{
    __shared__ float fs[800];        // 16 x 50
    __shared__ float u3loc[8000];    // 16 x 500
    __shared__ float red[2720];      // 16 x 10 x 17
    __shared__ float o2loc[160];
    __shared__ float o3loc[160];

    const int t   = threadIdx.x;
    const int blk = blockIdx.x;
    const int ks  = t & 15;
    const int il  = t >> 4;

    // stage f3 for 16 images
    for (int i = t; i < 800; i += 256) fs[i] = f3[(size_t)blk * 800 + i];
    __syncthreads();

    // lin500 -> u3loc (same per-(b,o) expression as round 10's role_lin500)
    for (int im = 0; im < 16; ++im) {
        for (int o = t; o < 500; o += 256) {
            float s = 0.f;
#pragma unroll
            for (int k = 0; k < 50; ++k) s += fs[im * 50 + k] * l1w[o * 50 + k];
            u3loc[im * 500 + o] = fmaxf(s + l1b[o], 0.f);
        }
    }

    // lin10-2 from v/vp (global, ldu=512)
    {
        const float* uu  = v  + (size_t)(blk * 16 + il) * 512;
        const float* uu2 = vp + (size_t)(blk * 16 + il) * 512;
        float acc[10];
#pragma unroll
        for (int o = 0; o < 10; ++o) acc[o] = 0.f;
        for (int i = 0; i < 31; ++i) {
            const int k = ks + i * 16;
            const float uv = uu[k] + uu2[k];
#pragma unroll
            for (int o = 0; o < 10; ++o) acc[o] += uv * l2c2w[o * 500 + k];
        }
        const int k = ks + 496;
        if (k < 500) {
            const float uv = uu[k] + uu2[k];
#pragma unroll
            for (int o = 0; o < 10; ++o) acc[o] += uv * l2c2w[o * 500 + k];
        }
        __syncthreads();   // u3loc writes done; red free to use
#pragma unroll
        for (int o = 0; o < 10; ++o) red[(il * 10 + o) * 17 + ks] = acc[o];
        __syncthreads();
        if (t < 160) {
            const int il2 = t / 10, o = t - il2 * 10;
            float s = 0.f;
#pragma unroll
            for (int q = 0; q < 16; ++q) s += red[(il2 * 10 + o) * 17 + q];
            o2loc[t] = s + l2c2b[o];
        }
        __syncthreads();
    }

    // lin10-3 from u3loc (LDS, ldu=500)
    {
        const float* uu = u3loc + il * 500;
        float acc[10];
#pragma unroll
        for (int o = 0; o < 10; ++o) acc[o] = 0.f;
        for (int i = 0; i < 31; ++i) {
            const int k = ks + i * 16;
            const float uv = uu[k];
#pragma unroll
            for (int o = 0; o < 10; ++o) acc[o] += uv * l2w[o * 500 + k];
        }
        const int k = ks + 496;
        if (k < 500) {
            const float uv = uu[k];
#pragma unroll
            for (int o = 0; o < 10; ++o) acc[o] += uv * l2w[o * 500 + k];
        }
#pragma unroll
        for (int o = 0; o < 10; ++o) red[(il * 10 + o) * 17 + ks] = acc[o];
        __syncthreads();
        if (t < 160) {
            const int il2 = t / 10, o = t - il2 * 10;
            float s = 0.f;
#pragma unroll
            for (int q = 0; q < 16; ++q) s += red[(il2 * 10 + o) * 17 + q];
            o3loc[t] = s + l2b[o];
        }
        __syncthreads();
    }

    // select + log_softmax (one thread per sample)
    if (t < 16) {
        const int b = blk * 16 + t;
        float vv[10];
        if (e1[b]) {
            const float* src = out1 + (size_t)b * 10;
#pragma unroll
            for (int o = 0; o < 10; ++o) vv[o] = src[o];
        } else if (e2[b]) {
#pragma unroll
            for (int o = 0; o < 10; ++o) vv[o] = o2loc[t * 10 + o];
        } else {
#pragma unroll
            for (int o = 0; o < 10; ++o) vv[o] = o3loc[t * 10 + o];
        }
        float m = -3.4e38f;
#pragma unroll
        for (int o = 0; o < 10; ++o) m = fmaxf(m, vv[o]);
        float s = 0.f;
#pragma unroll
        for (int o = 0; o < 10; ++o) s += expf(vv[o] - m);
        const float ls = logf(s);
#pragma unroll
        for (int o = 0; o < 10; ++o) out[(size_t)b * 10 + o] = vv[o] - m - ls;
    }
}

// ---------------------------------------------------------------------------
static inline size_t align256(size_t v) { return (v + 255) & ~(size_t)255; }

extern "C" void kernel_launch(void* const* d_in, const int* in_sizes, int n_in,
                              void* d_out, int out_size, void* d_ws, size_t ws_size,
                              hipStream_t stream)
{
    const float* x     = (const float*)d_in[0];
    const float* c1w   = (const float*)d_in[1];
    const float* c1b   = (const float*)d_in[2];
    const float* c2w   = (const float*)d_in[3];
    const float* c2b   = (const float*)d_in[4];
    const float* c3w   = (const float*)d_in[5];
    const float* c3b   = (const float*)d_in[6];
    const float* l1c1w = (const float*)d_in[7];
    const float* l1c1b = (const float*)d_in[8];
    const float* l2c1w = (const float*)d_in[9];
    const float* l2c1b = (const float*)d_in[10];
    const float* l1c2w = (const float*)d_in[11];
    const float* l1c2b = (const float*)d_in[12];
    const float* l2c2w = (const float*)d_in[13];
    const float* l2c2b = (const float*)d_in[14];
    const float* l1w   = (const float*)d_in[15];
    const float* l1b   = (const float*)d_in[16];
    const float* l2w   = (const float*)d_in[17];
    const float* l2b   = (const float*)d_in[18];
    const float* d1w   = (const float*)d_in[19];
    const float* d1b   = (const float*)d_in[20];
    const float* d2w   = (const float*)d_in[21];
    const float* d2b   = (const float*)d_in[22];

    // ---- workspace layout (single chunk, B=4096)
    size_t off = 0;
    const size_t oWb1  = off; off = align256(off + (size_t)512 * 8480 * 2);
    const size_t oWb2  = off; off = align256(off + (size_t)512 * 1280 * 2);
    const size_t oW2P  = off; off = align256(off + (size_t)50 * 600 * 4);
    const size_t oOut1 = off; off = align256(off + (size_t)B_IMG * 10 * 4);
    const size_t oE1   = off; off = align256(off + (size_t)B_IMG * 4);
    const size_t oE2   = off; off = align256(off + (size_t)B_IMG * 4);
    const size_t oH1   = off; off = align256(off + (size_t)B_IMG * 8480 * 4);
    const size_t oH2   = off; off = align256(off + (size_t)B_IMG * 1280 * 4);
    const size_t oU    = off; off = align256(off + (size_t)B_IMG * 512 * 4);
    const size_t oUP   = off; off = align256(off + (size_t)B_IMG * 512 * 4);
    const size_t oF3   = off; off = align256(off + (size_t)B_IMG * 50 * 4);
    const size_t oH1B  = off; off = align256(off + (size_t)B_IMG * 8480 * 2);
    const size_t oH2B  = off; off = align256(off + (size_t)B_IMG * 1280 * 2);

    char* ws = (char*)d_ws;
    bf16_t* Wb1  = (bf16_t*)(ws + oWb1);
    bf16_t* Wb2  = (bf16_t*)(ws + oWb2);
    float*  w2p  = (float*) (ws + oW2P);
    float*  out1 = (float*) (ws + oOut1);
    int*    e1   = (int*)   (ws + oE1);
    int*    e2   = (int*)   (ws + oE2);
    float*  h1   = (float*) (ws + oH1);
    float*  h2   = (float*) (ws + oH2);
    float*  u    = (float*) (ws + oU);
    float*  up   = (float*) (ws + oUP);
    float*  f3   = (float*) (ws + oF3);
    bf16_t* h1b  = (bf16_t*)(ws + oH1B);
    bf16_t* h2b  = (bf16_t*)(ws + oH2B);
    // stage-2 gemm outputs carved from the dead h1 region
    float*  v    = h1;                          // 4096*512 f32
    float*  vp   = h1 + (size_t)B_IMG * 512;    // 4096*512 f32

    float* out = (float*)d_out;

    // P: conv1 (+h1b mirror) + weight conversions (all independent)
    k_prep<<<5262, 256, 2048, stream>>>(x, c1w, c1b, h1, h1b,
                                        l1c1w, Wb1, l1c2w, Wb2, c2w, w2p);
    // A: gemm1(h1b) | conv2 | exit1  (r15-proven split, LDS 24832)
    k_stage1<<<8704, 256, 24832, stream>>>(h1, h1b, Wb1, l1c1b, u, up,
                                           d1w, d1b, e1, w2p, c2b, h2, h2b);
    // C: gemm2(h2b) | conv3+exit2 | lin10-1  (consume h2/h2b, stage1-u)
    k_stage2<<<1792, 256, 20000, stream>>>(h2, h2b, Wb2, l1c2b, v, vp, d2w, d2b, e2,
                                           c3w, c3b, f3, u, up, l2c1w, l2c1b, out1);
    // T: lin10-2 | lin500 | lin10-3 | select  (per-16-sample blocks)
    k_tail<<<256, 256, 0, stream>>>(v, vp, l2c2w, l2c2b, f3, l1w, l1b, l2w, l2b,
                                    out1, e1, e2, out);

    (void)in_sizes; (void)n_in; (void)out_size; (void)ws_size;
}

// Round 7
// 633.705 us; speedup vs baseline: 1.2336x; 1.0304x over previous
//
#include <hip/hip_runtime.h>
#include <hip/hip_bf16.h>
#include <cstdint>

// ---------------------------------------------------------------------------
// ThreeLayerCNN (BranchyNet early-exit), B=4096.
// Precision: conv1/conv2/exit1/exit2 fp32 (argmax parity with numpy ref);
// big FC GEMMs (l1c1, l1c2) bf16 MFMA w/ fp32 accum (output tol 0.146).
// Round 18 (r17 win confirmed the (oc,py) remap: conflicts 5.2e7->1.3e7,
// VGPR 48, stage1 465->400. Occupancy now LDS-capped at 6 blocks/CU):
//  - conv2 weights DIRECT from global w2p. In the (oc,py) mapping each
//    thread reads just 3 contiguous b128/ic (5-lane broadcast, 13 lines/
//    wave, 9.6KB chunk working set -> L1-resident). Weight LDS buffer +
//    its staging/prefetch deleted: conv2 LDS 24640 -> 5440 B.
//  - k_stage1 dynamic LDS 24832 -> 15488 (gemm floor) -> blocks/CU now
//    wave-capped at 8 (was LDS-capped 6); occupancy ceiling 75% -> 100%.
//  - r12's direct-weight failure was confounded (VGPR-cap spills, 15
//    reads/thread-ic in old mapping); this is the clean version.
//  - Everything else byte-identical to r17 (653 us best).
// ---------------------------------------------------------------------------

typedef __bf16 bf16_t;
typedef __bf16 bf16x8 __attribute__((ext_vector_type(8)));
typedef float  f32x4  __attribute__((ext_vector_type(4)));

#define B_IMG 4096

// ======================= role bodies (device functions) =====================

__device__ void role_conv1(char* smem, int blk,
    const float* __restrict__ x, const float* __restrict__ w1,
    const float* __restrict__ b1, float* __restrict__ h1,
    bf16_t* __restrict__ h1b)
{
    float* ws = (float*)smem;        // 450
    float* bs = ws + 456;            // 50
    const int t = threadIdx.x;
    for (int i = t; i < 450; i += 256) ws[i] = w1[i];
    if (t < 50) bs[t] = b1[t];
    __syncthreads();

    const int idx = blk * 256 + t;
    if (idx >= B_IMG * 169) return;
    const int b   = idx / 169;
    const int pos = idx % 169;
    const int py = pos / 13, px = pos % 13;

    const float* xp = x + (size_t)b * 784 + (2 * py) * 28 + 2 * px;
    float p[4][4];
#pragma unroll
    for (int r = 0; r < 4; ++r)
#pragma unroll
        for (int c = 0; c < 4; ++c) p[r][c] = xp[r * 28 + c];

    float*  hb  = h1  + (size_t)b * 8480 + pos;
    bf16_t* hbb = h1b + (size_t)b * 8480 + pos;
    if (pos < 30) {
        h1 [(size_t)b * 8480 + 8450 + pos] = 0.f;            // zero pad cols
        h1b[(size_t)b * 8480 + 8450 + pos] = (bf16_t)0.f;
    }

    for (int oc = 0; oc < 50; ++oc) {
        const float* wp = &ws[oc * 9];
        const float w00 = wp[0], w01 = wp[1], w02 = wp[2];
        const float w10 = wp[3], w11 = wp[4], w12 = wp[5];
        const float w20 = wp[6], w21 = wp[7], w22 = wp[8];
        float a[2][2];
#pragma unroll
        for (int dy = 0; dy < 2; ++dy)
#pragma unroll
            for (int dx = 0; dx < 2; ++dx) {
                a[dy][dx] = p[dy + 0][dx + 0] * w00 + p[dy + 0][dx + 1] * w01 + p[dy + 0][dx + 2] * w02
                          + p[dy + 1][dx + 0] * w10 + p[dy + 1][dx + 1] * w11 + p[dy + 1][dx + 2] * w12
                          + p[dy + 2][dx + 0] * w20 + p[dy + 2][dx + 1] * w21 + p[dy + 2][dx + 2] * w22;
            }
        float v = fmaxf(fmaxf(a[0][0], a[0][1]), fmaxf(a[1][0], a[1][1])) + bs[oc];
        const float r = fmaxf(v, 0.f);
        hb [oc * 169] = r;
        hbb[oc * 169] = (bf16_t)r;      // same RNE cast the gemm used to do
    }
}

// x8-vectorized fp32 -> bf16 weight conversion (pad cols/rows zeroed).
__device__ void role_wb16v8(int blk, const float* __restrict__ src,
                            bf16_t* __restrict__ dst, int N, int K, int Kp, int totalv)
{
    const int idx = blk * 256 + threadIdx.x;     // one thread per 8-elem group
    if (idx >= totalv) return;
    const int kg = Kp >> 3;
    const int n  = idx / kg;
    const int k0 = (idx - n * kg) * 8;
    bf16x8 v;
#pragma unroll
    for (int i = 0; i < 8; ++i) {
        const int k = k0 + i;
        const float f = (n < N && k < K) ? src[(size_t)n * K + k] : 0.f;
        v[i] = (bf16_t)f;
    }
    *(bf16x8*)&dst[(size_t)n * Kp + k0] = v;
}

__device__ void role_w2t(int blk, const float* __restrict__ w2, float* __restrict__ w2p)
{
    const int idx = blk * 256 + threadIdx.x;
    if (idx >= 50 * 600) return;
    const int ic = idx / 600, r = idx % 600, oc = r / 12, j = r % 12;
    w2p[idx] = (j < 9) ? w2[oc * 450 + ic * 9 + j] : 0.f;
}

// conv2 (50->50) + relu + pool; block per image, thread = (oc=t/5, py=t%5).
// Round-18: weights read DIRECT from global w2p (L1-resident 9.6KB/chunk,
// 3 contiguous b128 per thread-ic, 5-lane broadcast). Input-only LDS dbuf
// (in[2][680] = 5440 B). Per-output FP expression verbatim r17: row-major
// taps, ic order 0..49 -> h2 identical up to FMA contraction (as r17).
__device__ void role_conv2(char* smem, int b,
    const float* __restrict__ h1, const float* __restrict__ w2p,
    const float* __restrict__ b2, float* __restrict__ h2,
    bf16_t* __restrict__ h2b)
{
    float* in = (float*)smem;            // [2][680]
    const int t = threadIdx.x;

    // stage chunk 0 (ic 0..3)
    for (int s = t; s < 676; s += 256) in[s] = h1[(size_t)b * 8480 + s];
    __syncthreads();
    if (t < 30) {
        h2 [(size_t)b * 1280 + 1250 + t] = 0.f;
        h2b[(size_t)b * 1280 + 1250 + t] = (bf16_t)0.f;
    }

    const int oc = t / 5;                // 0..49 (wave: 13 distinct oc)
    const int py = t % 5;                // 0..4  (5-lane broadcast groups)
    const bool act = (t < 250);

    float acc[5][4];                     // [px][quad]
#pragma unroll
    for (int j = 0; j < 5; ++j)
#pragma unroll
        for (int q = 0; q < 4; ++q) acc[j][q] = 0.f;

    for (int ic0 = 0; ic0 < 50; ic0 += 4) {
        const int cur = (ic0 >> 2) & 1;
        if (ic0 + 4 < 50) {           // prefetch next <=4-ic input chunk
            const int nxt = cur ^ 1;
            const int nic2 = (50 - ic0 - 4 < 4) ? (50 - ic0 - 4) : 4;
            for (int s = t; s < nic2 * 169; s += 256)
                in[nxt * 680 + s] = h1[(size_t)b * 8480 + (ic0 + 4) * 169 + s];
        }
        if (act) {
            const int nic = (50 - ic0 < 4) ? (50 - ic0) : 4;
            const float* ibc = in + cur * 680 + (2 * py) * 13;     // row base
            const float* wcb = w2p + oc * 12;                       // GLOBAL
            for (int icl = 0; icl < nic; ++icl) {
                float row[4][13];
                const float* ip = ibc + icl * 169;
#pragma unroll
                for (int r = 0; r < 4; ++r)
#pragma unroll
                    for (int c = 0; c < 13; ++c) row[r][c] = ip[r * 13 + c];
                const float* wl = wcb + (size_t)(ic0 + icl) * 600;
                const f32x4 wv0 = *(const f32x4*)(wl);
                const f32x4 wv1 = *(const f32x4*)(wl + 4);
                const f32x4 wv2 = *(const f32x4*)(wl + 8);
                const float w00 = wv0[0], w01 = wv0[1], w02 = wv0[2];
                const float w10 = wv0[3], w11 = wv1[0], w12 = wv1[1];
                const float w20 = wv1[2], w21 = wv1[3], w22 = wv2[0];
#pragma unroll
                for (int px = 0; px < 5; ++px) {
                    const int c0 = 2 * px;
#pragma unroll
                    for (int dy = 0; dy < 2; ++dy)
#pragma unroll
                        for (int dx = 0; dx < 2; ++dx) {
                            acc[px][dy * 2 + dx] +=
                                  row[dy + 0][c0 + dx + 0] * w00 + row[dy + 0][c0 + dx + 1] * w01 + row[dy + 0][c0 + dx + 2] * w02
                                + row[dy + 1][c0 + dx + 0] * w10 + row[dy + 1][c0 + dx + 1] * w11 + row[dy + 1][c0 + dx + 2] * w12
                                + row[dy + 2][c0 + dx + 0] * w20 + row[dy + 2][c0 + dx + 1] * w21 + row[dy + 2][c0 + dx + 2] * w22;
                        }
                }
            }
        }
        __syncthreads();
    }

    if (act) {
#pragma unroll
        for (int px = 0; px < 5; ++px) {
            float v = fmaxf(fmaxf(acc[px][0], acc[px][1]), fmaxf(acc[px][2], acc[px][3]));
            const float r = fmaxf(v + b2[oc], 0.f);
            h2 [(size_t)b * 1280 + oc * 25 + py * 5 + px] = r;
            h2b[(size_t)b * 1280 + oc * 25 + py * 5 + px] = (bf16_t)r;
        }
    }
}

// conv3 + relu + pool + FOLDED exit2. 4 img/block; wave il == image il,
// so exit2 is a pure shuffle reduce (no barrier, no LDS).
__device__ void role_conv3x(char* smem, int blk,
    const float* __restrict__ h2, const float* __restrict__ w3,
    const float* __restrict__ b3,
    const float* __restrict__ d2w, const float* __restrict__ d2b,
    int* __restrict__ e2, float* __restrict__ f3)
{
    float* in = (float*)smem;    // 5000
    const int t = threadIdx.x;
    for (int i = t; i < 5000; i += 256) {
        const int img = i / 1250, off = i % 1250;
        in[i] = h2[(size_t)(blk * 4 + img) * 1280 + off];
    }
    __syncthreads();
    const int il   = t >> 6;
    const int lane = t & 63;

    // folded exit2: one wave per image, strided dot + shuffle tree
    {
        const float* ip = &in[il * 1250];
        float s0 = 0.f, s1 = 0.f;
        for (int i = lane; i < 1250; i += 64) {
            const float vv = ip[i];
            s0 += vv * d2w[i];
            s1 += vv * d2w[1250 + i];
        }
#pragma unroll
        for (int off = 32; off > 0; off >>= 1) {
            s0 += __shfl_down(s0, off);
            s1 += __shfl_down(s1, off);
        }
        if (lane == 0) e2[blk * 4 + il] = (s0 + d2b[0] >= s1 + d2b[1]) ? 1 : 0;
    }

    const int oc = lane;
    if (oc >= 50) return;

    const float* ip0 = &in[il * 1250];
    float a00 = 0.f, a01 = 0.f, a10 = 0.f, a11 = 0.f;
    for (int ic = 0; ic < 50; ++ic) {
        float p[4][4];
        const float* ip = ip0 + ic * 25;
#pragma unroll
        for (int r = 0; r < 4; ++r)
#pragma unroll
            for (int c = 0; c < 4; ++c) p[r][c] = ip[r * 5 + c];
        const float* wp = &w3[((size_t)oc * 50 + ic) * 9];
        const float w00 = wp[0], w01 = wp[1], w02 = wp[2];
        const float w10 = wp[3], w11 = wp[4], w12 = wp[5];
        const float w20 = wp[6], w21 = wp[7], w22 = wp[8];
        a00 += p[0][0]*w00 + p[0][1]*w01 + p[0][2]*w02 + p[1][0]*w10 + p[1][1]*w11 + p[1][2]*w12 + p[2][0]*w20 + p[2][1]*w21 + p[2][2]*w22;
        a01 += p[0][1]*w00 + p[0][2]*w01 + p[0][3]*w02 + p[1][1]*w10 + p[1][2]*w11 + p[1][3]*w12 + p[2][1]*w20 + p[2][2]*w21 + p[2][3]*w22;
        a10 += p[1][0]*w00 + p[1][1]*w01 + p[1][2]*w02 + p[2][0]*w10 + p[2][1]*w11 + p[2][2]*w12 + p[3][0]*w20 + p[3][1]*w21 + p[3][2]*w22;
        a11 += p[1][1]*w00 + p[1][2]*w01 + p[1][3]*w02 + p[2][1]*w10 + p[2][2]*w11 + p[2][3]*w12 + p[3][1]*w20 + p[3][2]*w21 + p[3][3]*w22;
    }
    float v = fmaxf(fmaxf(a00, a01), fmaxf(a10, a11)) + b3[oc];
    f3[(size_t)(blk * 4 + il) * 50 + oc] = fmaxf(v, 0.f);
}

__device__ void role_exit(char* smem, int b,
    const float* __restrict__ F, int ldf, int K,
    const float* __restrict__ dw, const float* __restrict__ db, int* __restrict__ e)
{
    float* r0 = (float*)smem;   // 256
    float* r1 = r0 + 256;       // 256
    const int t = threadIdx.x;
    const float* f = F + (size_t)b * ldf;
    float s0 = 0.f, s1 = 0.f;
    for (int i = t; i < K; i += 256) {
        const float v = f[i];
        s0 += v * dw[i];
        s1 += v * dw[K + i];
    }
    r0[t] = s0; r1[t] = s1;
    __syncthreads();
    for (int s = 128; s > 0; s >>= 1) {
        if (t < s) { r0[t] += r0[t + s]; r1[t] += r1[t + s]; }
        __syncthreads();
    }
    if (t == 0) e[b] = (r0[0] + db[0] >= r1[0] + db[1]) ? 1 : 0;
}

// MFMA GEMM split-K=2 (r9-proven schedule). A is PRE-CONVERTED bf16
// (h1b/h2b): staging is a bare uint4 copy, no cvt chain, half the bytes.
__device__ void role_gemm(char* smem, int g,
    const bf16_t* __restrict__ A, int lda, const bf16_t* __restrict__ W,
    const float* __restrict__ bias, float* __restrict__ C0, float* __restrict__ C1,
    int Kp, int khalf, int Nout, int ldc)
{
    bf16_t* As = (bf16_t*)smem;      // 128*40
    bf16_t* Bs = As + 128 * 40;      // 64*40

    const int t = threadIdx.x;
    const int m0 = (g & 31) * 128;
    const int n0 = ((g >> 5) & 7) * 64;
    const int kz = g >> 8;
    const int kbeg = kz ? khalf : 0;
    const int kend = kz ? Kp : khalf;
    float* C = kz ? C1 : C0;

    const int wave = t >> 6;
    const int lane = t & 63;
    const int wm = (wave >> 1) * 64;
    const int wn = (wave & 1) * 32;
    const int quad = lane >> 4;
    const int lr = lane & 15;

    f32x4 acc[4][2];
#pragma unroll
    for (int i = 0; i < 4; ++i)
#pragma unroll
        for (int j = 0; j < 2; ++j) acc[i][j] = (f32x4)0.f;

    const int ar = t >> 2;
    const int ac = (t & 3) * 8;

    for (int k0 = kbeg; k0 < kend; k0 += 32) {
        __syncthreads();
#pragma unroll
        for (int h = 0; h < 2; ++h) {
            *(uint4*)&As[(ar + h * 64) * 40 + ac] =
                *(const uint4*)&A[(size_t)(m0 + ar + h * 64) * lda + k0 + ac];
        }
        *(uint4*)&Bs[ar * 40 + ac] = *(const uint4*)&W[(size_t)(n0 + ar) * Kp + k0 + ac];
        __syncthreads();

        bf16x8 af[4], bfr[2];
#pragma unroll
        for (int i = 0; i < 4; ++i)
            af[i] = *(const bf16x8*)&As[(wm + i * 16 + lr) * 40 + quad * 8];
#pragma unroll
        for (int j = 0; j < 2; ++j)
            bfr[j] = *(const bf16x8*)&Bs[(wn + j * 16 + lr) * 40 + quad * 8];
#pragma unroll
        for (int i = 0; i < 4; ++i)
#pragma unroll
            for (int j = 0; j < 2; ++j)
                acc[i][j] = __builtin_amdgcn_mfma_f32_16x16x32_bf16(af[i], bfr[j], acc[i][j], 0, 0, 0);
    }

#pragma unroll
    for (int j = 0; j < 2; ++j) {
        const int n = n0 + wn + j * 16 + lr;
        const float bv = (kz == 0 && n < Nout) ? bias[n] : 0.f;
#pragma unroll
        for (int i = 0; i < 4; ++i) {
            const int mrow = m0 + wm + i * 16 + quad * 4;
#pragma unroll
            for (int r = 0; r < 4; ++r)
                C[(size_t)(mrow + r) * ldc + n] = acc[i][j][r] + bv;
        }
    }
}

// lin10: out[b,o<10] = (U[+U2]) @ W^T + bias; 16 img x 16 k-strips per block.
__device__ void role_lin10(char* smem, int blk,
    const float* __restrict__ U, const float* __restrict__ U2, int ldu,
    const float* __restrict__ W, const float* __restrict__ bias,
    float* __restrict__ out)
{
    float* red = (float*)smem;   // [16][10][17]
    const int t = threadIdx.x;
    const int ks = t & 15;
    const int il = t >> 4;
    const int b  = blk * 16 + il;
    const float* u = U + (size_t)b * ldu;

    float acc[10];
#pragma unroll
    for (int o = 0; o < 10; ++o) acc[o] = 0.f;

    if (U2) {
        const float* u2 = U2 + (size_t)b * ldu;
        for (int i = 0; i < 31; ++i) {
            const int k = ks + i * 16;
            const float uv = u[k] + u2[k];
#pragma unroll
            for (int o = 0; o < 10; ++o) acc[o] += uv * W[o * 500 + k];
        }
        const int k = ks + 496;
        if (k < 500) {
            const float uv = u[k] + u2[k];
#pragma unroll
            for (int o = 0; o < 10; ++o) acc[o] += uv * W[o * 500 + k];
        }
    } else {
        for (int i = 0; i < 31; ++i) {
            const int k = ks + i * 16;
            const float uv = u[k];
#pragma unroll
            for (int o = 0; o < 10; ++o) acc[o] += uv * W[o * 500 + k];
        }
        const int k = ks + 496;
        if (k < 500) {
            const float uv = u[k];
#pragma unroll
            for (int o = 0; o < 10; ++o) acc[o] += uv * W[o * 500 + k];
        }
    }
#pragma unroll
    for (int o = 0; o < 10; ++o) red[(il * 10 + o) * 17 + ks] = acc[o];
    __syncthreads();
    if (t < 160) {
        const int il2 = t / 10, o = t - il2 * 10;
        float s = 0.f;
#pragma unroll
        for (int q = 0; q < 16; ++q) s += red[(il2 * 10 + o) * 17 + q];
        out[(size_t)(blk * 16 + il2) * 10 + o] = s + bias[o];
    }
}

// ============================ fused kernels ================================

__global__ __launch_bounds__(256) void k_prep(
    const float* x, const float* c1w, const float* c1b, float* h1, bf16_t* h1b,
    const float* l1c1w, bf16_t* Wb1, const float* l1c2w, bf16_t* Wb2,
    const float* c2w, float* w2p)
{
    extern __shared__ char smem[];
    const int g = blockIdx.x;
    if (g < 2704)        role_conv1(smem, g, x, c1w, c1b, h1, h1b);
    else if (g < 4824)   role_wb16v8(g - 2704, l1c1w, Wb1, 500, 8450, 8480, 512 * 1060);
    else if (g < 5144)   role_wb16v8(g - 4824, l1c2w, Wb2, 500, 1250, 1280, 512 * 160);
    else                 role_w2t(g - 5144, c2w, w2p);
}

__global__ __launch_bounds__(256) void k_stage1(
    const float* h1, const bf16_t* h1b, const bf16_t* Wb1, const float* l1c1b,
    float* u, float* up,
    const float* d1w, const float* d1b, int* e1,
    const float* w2p, const float* c2b, float* h2, bf16_t* h2b)
{
    extern __shared__ char smem[];
    const int g = blockIdx.x;
    if (g < 512)         role_gemm(smem, g, h1b, 8480, Wb1, l1c1b, u, up, 8480, 4256, 500, 512);
    else if (g < 4608)   role_conv2(smem, g - 512, h1, w2p, c2b, h2, h2b);
    else                 role_exit(smem, g - 4608, h1, 8480, 8450, d1w, d1b, e1);
}

__global__ __launch_bounds__(256) void k_stage2(
    const float* h2, const bf16_t* h2b, const bf16_t* Wb2, const float* l1c2b,
    float* v, float* vp,
    const float* d2w, const float* d2b, int* e2,
    const float* c3w, const float* c3b, float* f3,
    const float* u, const float* up, const float* l2c1w, const float* l2c1b, float* out1)
{
    extern __shared__ char smem[];
    const int g = blockIdx.x;
    if (g < 512)         role_gemm(smem, g, h2b, 1280, Wb2, l1c2b, v, vp, 1280, 640, 500, 512);
    else if (g < 1536)   role_conv3x(smem, g - 512, h2, c3w, c3b, d2w, d2b, e2, f3);
    else                 role_lin10(smem, g - 1536, u, up, 512, l2c1w, l2c1b, out1);
}

// k_tail: per block = 16 samples. lin10-2 (v/vp) -> o2loc; lin500 -> u3 LDS;
// lin10-3 (u3 LDS) -> o3loc; select + log_softmax -> out. FP per-(b,o)
// expressions identical to round 10's separate kernels.
__global__ __launch_bounds__(256) void k_tail(
    const float* __restrict__ v, const float* __restrict__ vp,
    const float* __restrict__ l2c2w, const float* __restrict__ l2c2b,
    const float* __restrict__ f3, const float* __restrict__ l1w, const float* __restrict__ l1b,
    const float* __restrict__ l2w, const float* __restrict__ l2b,
    const float* __restrict__ out1, const int* __restrict__ e1, const int* __restrict__ e2,
    float* __restrict__ out)
{
    __shared__ float fs[800];        // 16 x 50
    __shared__ float u3loc[8000];    // 16 x 500
    __shared__ float red[2720];      // 16 x 10 x 17
    __shared__ float o2loc[160];
    __shared__ float o3loc[160];

    const int t   = threadIdx.x;
    const int blk = blockIdx.x;
    const int ks  = t & 15;
    const int il  = t >> 4;

    // stage f3 for 16 images
    for (int i = t; i < 800; i += 256) fs[i] = f3[(size_t)blk * 800 + i];
    __syncthreads();

    // lin500 -> u3loc (same per-(b,o) expression as round 10's role_lin500)
    for (int im = 0; im < 16; ++im) {
        for (int o = t; o < 500; o += 256) {
            float s = 0.f;
#pragma unroll
            for (int k = 0; k < 50; ++k) s += fs[im * 50 + k] * l1w[o * 50 + k];
            u3loc[im * 500 + o] = fmaxf(s + l1b[o], 0.f);
        }
    }

    // lin10-2 from v/vp (global, ldu=512)
    {
        const float* uu  = v  + (size_t)(blk * 16 + il) * 512;
        const float* uu2 = vp + (size_t)(blk * 16 + il) * 512;
        float acc[10];
#pragma unroll
        for (int o = 0; o < 10; ++o) acc[o] = 0.f;
        for (int i = 0; i < 31; ++i) {
            const int k = ks + i * 16;
            const float uv = uu[k] + uu2[k];
#pragma unroll
            for (int o = 0; o < 10; ++o) acc[o] += uv * l2c2w[o * 500 + k];
        }
        const int k = ks + 496;
        if (k < 500) {
            const float uv = uu[k] + uu2[k];
#pragma unroll
            for (int o = 0; o < 10; ++o) acc[o] += uv * l2c2w[o * 500 + k];
        }
        __syncthreads();   // u3loc writes done; red free to use
#pragma unroll
        for (int o = 0; o < 10; ++o) red[(il * 10 + o) * 17 + ks] = acc[o];
        __syncthreads();
        if (t < 160) {
            const int il2 = t / 10, o = t - il2 * 10;
            float s = 0.f;
#pragma unroll
            for (int q = 0; q < 16; ++q) s += red[(il2 * 10 + o) * 17 + q];
            o2loc[t] = s + l2c2b[o];
        }
        __syncthreads();
    }

    // lin10-3 from u3loc (LDS, ldu=500)
    {
        const float* uu = u3loc + il * 500;
        float acc[10];
#pragma unroll
        for (int o = 0; o < 10; ++o) acc[o] = 0.f;
        for (int i = 0; i < 31; ++i) {
            const int k = ks + i * 16;
            const float uv = uu[k];
#pragma unroll
            for (int o = 0; o < 10; ++o) acc[o] += uv * l2w[o * 500 + k];
        }
        const int k = ks + 496;
        if (k < 500) {
            const float uv = uu[k];
#pragma unroll
            for (int o = 0; o < 10; ++o) acc[o] += uv * l2w[o * 500 + k];
        }
#pragma unroll
        for (int o = 0; o < 10; ++o) red[(il * 10 + o) * 17 + ks] = acc[o];
        __syncthreads();
        if (t < 160) {
            const int il2 = t / 10, o = t - il2 * 10;
            float s = 0.f;
#pragma unroll
            for (int q = 0; q < 16; ++q) s += red[(il2 * 10 + o) * 17 + q];
            o3loc[t] = s + l2b[o];
        }
        __syncthreads();
    }

    // select + log_softmax (one thread per sample)
    if (t < 16) {
        const int b = blk * 16 + t;
        float vv[10];
        if (e1[b]) {
            const float* src = out1 + (size_t)b * 10;
#pragma unroll
            for (int o = 0; o < 10; ++o) vv[o] = src[o];
        } else if (e2[b]) {
#pragma unroll
            for (int o = 0; o < 10; ++o) vv[o] = o2loc[t * 10 + o];
        } else {
#pragma unroll
            for (int o = 0; o < 10; ++o) vv[o] = o3loc[t * 10 + o];
        }
        float m = -3.4e38f;
#pragma unroll
        for (int o = 0; o < 10; ++o) m = fmaxf(m, vv[o]);
        float s = 0.f;
#pragma unroll
        for (int o = 0; o < 10; ++o) s += expf(vv[o] - m);
        const float ls = logf(s);
#pragma unroll
        for (int o = 0; o < 10; ++o) out[(size_t)b * 10 + o] = vv[o] - m - ls;
    }
}

// ---------------------------------------------------------------------------
static inline size_t align256(size_t v) { return (v + 255) & ~(size_t)255; }

extern "C" void kernel_launch(void* const* d_in, const int* in_sizes, int n_in,
                              void* d_out, int out_size, void* d_ws, size_t ws_size,
                              hipStream_t stream)
{
    const float* x     = (const float*)d_in[0];
    const float* c1w   = (const float*)d_in[1];
    const float* c1b   = (const float*)d_in[2];
    const float* c2w   = (const float*)d_in[3];
    const float* c2b   = (const float*)d_in[4];
    const float* c3w   = (const float*)d_in[5];
    const float* c3b   = (const float*)d_in[6];
    const float* l1c1w = (const float*)d_in[7];
    const float* l1c1b = (const float*)d_in[8];
    const float* l2c1w = (const float*)d_in[9];
    const float* l2c1b = (const float*)d_in[10];
    const float* l1c2w = (const float*)d_in[11];
    const float* l1c2b = (const float*)d_in[12];
    const float* l2c2w = (const float*)d_in[13];
    const float* l2c2b = (const float*)d_in[14];
    const float* l1w   = (const float*)d_in[15];
    const float* l1b   = (const float*)d_in[16];
    const float* l2w   = (const float*)d_in[17];
    const float* l2b   = (const float*)d_in[18];
    const float* d1w   = (const float*)d_in[19];
    const float* d1b   = (const float*)d_in[20];
    const float* d2w   = (const float*)d_in[21];
    const float* d2b   = (const float*)d_in[22];

    // ---- workspace layout (single chunk, B=4096)
    size_t off = 0;
    const size_t oWb1  = off; off = align256(off + (size_t)512 * 8480 * 2);
    const size_t oWb2  = off; off = align256(off + (size_t)512 * 1280 * 2);
    const size_t oW2P  = off; off = align256(off + (size_t)50 * 600 * 4);
    const size_t oOut1 = off; off = align256(off + (size_t)B_IMG * 10 * 4);
    const size_t oE1   = off; off = align256(off + (size_t)B_IMG * 4);
    const size_t oE2   = off; off = align256(off + (size_t)B_IMG * 4);
    const size_t oH1   = off; off = align256(off + (size_t)B_IMG * 8480 * 4);
    const size_t oH2   = off; off = align256(off + (size_t)B_IMG * 1280 * 4);
    const size_t oU    = off; off = align256(off + (size_t)B_IMG * 512 * 4);
    const size_t oUP   = off; off = align256(off + (size_t)B_IMG * 512 * 4);
    const size_t oF3   = off; off = align256(off + (size_t)B_IMG * 50 * 4);
    const size_t oH1B  = off; off = align256(off + (size_t)B_IMG * 8480 * 2);
    const size_t oH2B  = off; off = align256(off + (size_t)B_IMG * 1280 * 2);

    char* ws = (char*)d_ws;
    bf16_t* Wb1  = (bf16_t*)(ws + oWb1);
    bf16_t* Wb2  = (bf16_t*)(ws + oWb2);
    float*  w2p  = (float*) (ws + oW2P);
    float*  out1 = (float*) (ws + oOut1);
    int*    e1   = (int*)   (ws + oE1);
    int*    e2   = (int*)   (ws + oE2);
    float*  h1   = (float*) (ws + oH1);
    float*  h2   = (float*) (ws + oH2);
    float*  u    = (float*) (ws + oU);
    float*  up   = (float*) (ws + oUP);
    float*  f3   = (float*) (ws + oF3);
    bf16_t* h1b  = (bf16_t*)(ws + oH1B);
    bf16_t* h2b  = (bf16_t*)(ws + oH2B);
    // stage-2 gemm outputs carved from the dead h1 region
    float*  v    = h1;                          // 4096*512 f32
    float*  vp   = h1 + (size_t)B_IMG * 512;    // 4096*512 f32

    float* out = (float*)d_out;

    // P: conv1 (+h1b mirror) + weight conversions (all independent)
    k_prep<<<5262, 256, 2048, stream>>>(x, c1w, c1b, h1, h1b,
                                        l1c1w, Wb1, l1c2w, Wb2, c2w, w2p);
    // A: gemm1(h1b) | conv2 (direct-global weights) | exit1; LDS 15488
    k_stage1<<<8704, 256, 15488, stream>>>(h1, h1b, Wb1, l1c1b, u, up,
                                           d1w, d1b, e1, w2p, c2b, h2, h2b);
    // C: gemm2(h2b) | conv3+exit2 | lin10-1  (consume h2/h2b, stage1-u)
    k_stage2<<<1792, 256, 20000, stream>>>(h2, h2b, Wb2, l1c2b, v, vp, d2w, d2b, e2,
                                           c3w, c3b, f3, u, up, l2c1w, l2c1b, out1);
    // T: lin10-2 | lin500 | lin10-3 | select  (per-16-sample blocks)
    k_tail<<<256, 256, 0, stream>>>(v, vp, l2c2w, l2c2b, f3, l1w, l1b, l2w, l2b,
                                    out1, e1, e2, out);

    (void)in_sizes; (void)n_in; (void)out_size; (void)ws_size;
}